// Round 12
// baseline (4984.941 us; speedup 1.0000x reference)
//
#include <hip/hip_runtime.h>
#include <hip/hip_bf16.h>

// 2-layer GRU decoder, persistent MFMA kernel. B=128, T=1024, H=200.
// R15: 2-WAY TEMPORAL MULTIPLEXING. 16 batch-groups x 8 batches; each of the
// 128 blocks (8 block-cols x 16 slices) serves TWO groups, A=g and B=g+8,
// phase-shifted half a step. Every LLC round trip in one group's chain
// (stage-RT, drain-RT, flag-detect) hides under the other group's compute:
//   iter t: [unpack A][MFMA A (poll-B prefetched)][check B][issue B loads]
//           [gates A][sync=drain A-stores+B-loads][flag A]
//           [unpack B][MFMA B (poll-A prefetched)][check A][issue A(t+1)]
//           [gates B][sync=drain][flag B]
// MFMA uses 8 valid batch cols (cols 8-15 read a zeroed row; outputs unread).
// All primitives R13-proven: system-scope dword exchange, tid0 flag after a
// full-sync drain, ONE sleepy bounded 16-lane poll wave per block.
// Poll prefetch: issue flag loads before the MFMA phase, first check after it
// -> other group's flags are ~half an iteration old -> detect ~0 exposed.
// Flags extend to 16 groups (1024 u32 @ws+102400; ws>=819200B proven R10/R11).
// Ledger: R3 3157 -> R8 2998 (flag barrier) -> R13 2926 (store remap).
// Lessons held: scope no lever (R9); RMWs pipeline (R8); load-side layout
// untouchable (R11); staging is RT-bound not issue-bound (R14); poll = one
// sleepy wave/block (R7/R10/R12).

#define TT 1024
#define HH 200
#define HS 13
#define KP 232   // hB row stride in ushorts; 464 B = 29*16 -> b128-aligned

typedef __attribute__((ext_vector_type(8))) short short8;
typedef __attribute__((ext_vector_type(4))) float f32x4;

__device__ __forceinline__ float sigm(float v) { return 1.0f / (1.0f + __expf(-v)); }
__device__ __forceinline__ float tanh_fast(float v) {
  float e = __expf(-2.0f * v);
  return (1.0f - e) / (1.0f + e);
}
__device__ __forceinline__ uint llc_load_u32(const uint* p) {
  return __hip_atomic_load(p, __ATOMIC_RELAXED, __HIP_MEMORY_SCOPE_SYSTEM);
}
__device__ __forceinline__ void llc_store_u32(uint* p, uint v) {
  __hip_atomic_store(p, v, __ATOMIC_RELAXED, __HIP_MEMORY_SCOPE_SYSTEM);
}
__device__ __forceinline__ float bfu2f(ushort u) {
  return __uint_as_float(((uint)u) << 16);
}
__device__ __forceinline__ ushort f2bfu(float f) {
  __hip_bfloat16 b = __float2bfloat16(f);
  return *(ushort*)&b;
}
__device__ __forceinline__ uint packf(float h) {
  ushort hi = f2bfu(h);
  float  fh = bfu2f(hi);
  ushort lo = f2bfu(h - fh);
  return (uint)hi | ((uint)lo << 16);
}

__global__ __launch_bounds__(256, 1) void gru2_mfma(
    const float* __restrict__ x,
    const float* __restrict__ Wih0, const float* __restrict__ Whh0,
    const float* __restrict__ bih0, const float* __restrict__ bhh0,
    const float* __restrict__ Wih1, const float* __restrict__ Whh1,
    const float* __restrict__ bih1, const float* __restrict__ bhh1,
    const float* __restrict__ Wfc,  const float* __restrict__ bfc,
    float* __restrict__ out,
    uint* __restrict__ h0g, uint* __restrict__ h1g, uint* __restrict__ syncp)
{
  // LDS: per-group bf16 hi/lo planes of h0,h1 (8 batches each), zero row for
  // MFMA cols 8-15, D results, gate tables.
  __shared__ __align__(16) ushort hBh[2][2][8][KP];   // [state][grp][b][k]
  __shared__ __align__(16) ushort hBl[2][2][8][KP];
  __shared__ __align__(16) ushort zrh[KP], zrl[KP];
  __shared__ float D[117][17];
  __shared__ float Wi0t[8][39];
  __shared__ float bi0[39], bh0[39], bi1[39], bh1[39], bfs[4];
  __shared__ float xc[2][8][8];

  const int tid  = threadIdx.x;
  const int wave = tid >> 6;
  const int lane = tid & 63;
  const int m15  = lane & 15;
  const int q    = lane >> 4;

  const int blkg = blockIdx.x & 7;    // block column
  const int s    = blockIdx.x >> 3;   // hidden-slice
  const int gA   = blkg,      gB  = blkg + 8;   // group ids (0..15)
  const int bbA  = gA * 8,    bbB = gB * 8;     // batch bases
  const int j0 = s * HS;
  const int hs = (HH - j0 < HS) ? (HH - j0) : HS;   // 13 or 5 (s==15)
  const int th   = 3 * hs;
  const int h0r  = 6 * hs;
  const int T0   = (h0r + 15) >> 4;
  const int NT   = T0 + ((th + 15) >> 4);
  const bool isOut = (s == 15);

  // flags (1024 u32 @ syncp): flag(gr,s) at gr*64 + s*4 (16B spacing).
  uint* flags = syncp;

  // ---- one-time: weight A-fragments into registers (slice-based; same) ----
  short8 Ah[2][7], Al[2][7];
  #pragma unroll
  for (int mt = 0; mt < 2; ++mt) {
    const int T = wave * 2 + mt;
    const bool fc  = isOut && (wave == 2) && (mt == 0);
    const bool val = fc || (T < NT);
    #pragma unroll
    for (int kt = 0; kt < 7; ++kt) {
      short8 vh = {0,0,0,0,0,0,0,0}, vl = {0,0,0,0,0,0,0,0};
      #pragma unroll
      for (int j = 0; j < 8; ++j) {
        const int k = kt * 32 + q * 8 + j;
        float w = 0.0f;
        if (val && k < HH) {
          if (fc) {
            if (m15 < 4) w = Wfc[m15 * HH + k];
          } else {
            const int p = T * 16 + m15;
            int r = -1;
            if (p < h0r) r = p;
            else if (p >= T0 * 16 && (p - T0 * 16) < th) r = h0r + (p - T0 * 16);
            if (r >= 0) {
              const int m  = r / th, rr = r - m * th;
              const int qq = rr / hs, jj = rr - qq * hs;
              const float* src = (m == 0) ? Whh0 : ((m == 1) ? Wih1 : Whh1);
              w = src[(qq * HH + j0 + jj) * HH + k];
            }
          }
        }
        const ushort uh = f2bfu(w);
        const ushort ul = f2bfu(w - bfu2f(uh));
        vh[j] = (short)uh; vl[j] = (short)ul;
      }
      Ah[mt][kt] = vh; Al[mt][kt] = vl;
    }
  }

  // ---- one-time: LDS tables + zero init ----
  for (int u = tid; u < th * 8; u += 256) {
    int rr = u >> 3, c = u & 7;
    int qq = rr / hs, jj = rr - qq * hs;
    Wi0t[c][rr] = Wih0[(qq * HH + j0 + jj) * 8 + c];
  }
  for (int u = tid; u < th; u += 256) {
    int qq = u / hs, jj = u - qq * hs;
    int grow = qq * HH + j0 + jj;
    bi0[u] = bih0[grow]; bh0[u] = bhh0[grow];
    bi1[u] = bih1[grow]; bh1[u] = bhh1[grow];
  }
  if (tid < 4) bfs[tid] = bfc[tid];
  for (int u = tid; u < 2 * 2 * 8 * KP / 2; u += 256) ((uint*)hBh)[u] = 0;
  for (int u = tid; u < 2 * 2 * 8 * KP / 2; u += 256) ((uint*)hBl)[u] = 0;
  for (int u = tid; u < KP / 2; u += 256) { ((uint*)zrh)[u] = 0; ((uint*)zrl)[u] = 0; }
  // Emotion columns (t-invariant): 2 groups x 8 b x 4 c = 64 threads.
  if (tid < 64) {
    const int gi = tid >> 5, rem = tid & 31, b = rem >> 2, c = 4 + (rem & 3);
    const int bb = gi ? bbB : bbA;
    xc[gi][b][c] = x[(bb + b) * TT * 8 + c];
  }
  __syncthreads();

  // ---- helpers ----
  auto issue_w = [&](uint* w, int bb, int tau) {   // stage h for step tau
    const uint* p0 = h0g + ((tau + 1) & 1) * 25600;
    const uint* p1 = h1g + (tau & 1) * 25600;
    #pragma unroll
    for (int i = 0; i < 13; ++i) {
      if (i < 12 || tid < 128) {
        const int u = tid + i * 256;             // 3200 = 2st x 8b x 200k
        const int st = u / 1600, rem = u - st * 1600;
        const int b = rem / 200, k = rem - b * 200;
        w[i] = llc_load_u32(&(st ? p1 : p0)[(bb + b) * HH + k]);
      }
    }
  };
  auto unpack_w = [&](const uint* w, int gi) {
    #pragma unroll
    for (int i = 0; i < 13; ++i) {
      if (i < 12 || tid < 128) {
        const int u = tid + i * 256;
        const int st = u / 1600, rem = u - st * 1600;
        const int b = rem / 200, k = rem - b * 200;
        hBh[st][gi][b][k] = (ushort)(w[i] & 0xffff);
        hBl[st][gi][b][k] = (ushort)(w[i] >> 16);
      }
    }
  };
  auto mfma_phase = [&](int gi, int bb, int t) {
    #pragma unroll
    for (int mt = 0; mt < 2; ++mt) {
      const int T = wave * 2 + mt;
      const bool fc  = isOut && (wave == 2) && (mt == 0);
      const bool val = fc || (T < NT);
      if (!val) continue;
      const int st = fc ? 1 : ((T < T0) ? 0 : 1);
      const ushort* Bh = (m15 < 8) ? &hBh[st][gi][m15][0] : zrh;
      const ushort* Bl = (m15 < 8) ? &hBl[st][gi][m15][0] : zrl;
      f32x4 acc = {0.f, 0.f, 0.f, 0.f};
      #pragma unroll
      for (int kt = 0; kt < 7; ++kt) {
        const short8 bh = *(const short8*)&Bh[kt * 32 + q * 8];
        const short8 bl = *(const short8*)&Bl[kt * 32 + q * 8];
        acc = __builtin_amdgcn_mfma_f32_16x16x32_bf16(Ah[mt][kt], bh, acc, 0, 0, 0);
        acc = __builtin_amdgcn_mfma_f32_16x16x32_bf16(Ah[mt][kt], bl, acc, 0, 0, 0);
        acc = __builtin_amdgcn_mfma_f32_16x16x32_bf16(Al[mt][kt], bh, acc, 0, 0, 0);
      }
      if (fc) {
        if (t >= 2 && m15 < 8) {
          #pragma unroll
          for (int i = 0; i < 4; ++i) {
            const int p = q * 4 + i;
            if (p < 4)
              out[((bb + m15) * TT + (t - 2)) * 4 + p] = tanh_fast(acc[i] + bfs[p]);
          }
        }
      } else {
        #pragma unroll
        for (int i = 0; i < 4; ++i) {
          const int p = T * 16 + q * 4 + i;
          int r = -1;
          if (p < h0r) r = p;
          else if (p >= T0 * 16 && (p - T0 * 16) < th) r = h0r + (p - T0 * 16);
          if (r >= 0) D[r][m15] = acc[i];
        }
      }
    }
  };
  const int gcb = tid / hs, gcj = tid - gcb * hs;   // gate indices (cb<8 used)
  auto gates_phase = [&](int gi, int bb, int t) {
    if (tid < 8 * hs) {
      const float hv0 = bfu2f(hBh[0][gi][gcb][j0 + gcj]) + bfu2f(hBl[0][gi][gcb][j0 + gcj]);
      const float hv1 = bfu2f(hBh[1][gi][gcb][j0 + gcj]) + bfu2f(hBl[1][gi][gcb][j0 + gcj]);
      if (t < TT) {                       // h0(t)
        float ir = bi0[gcj], iz = bi0[hs + gcj], in_ = bi0[2 * hs + gcj];
        #pragma unroll
        for (int c = 0; c < 8; ++c) {
          const float xv = xc[gi][gcb][c];
          ir  += Wi0t[c][gcj] * xv;
          iz  += Wi0t[c][hs + gcj] * xv;
          in_ += Wi0t[c][2 * hs + gcj] * xv;
        }
        const float hr = D[gcj][gcb] + bh0[gcj];
        const float hz = D[hs + gcj][gcb] + bh0[hs + gcj];
        const float hn = D[2 * hs + gcj][gcb] + bh0[2 * hs + gcj];
        const float r = sigm(ir + hr), z = sigm(iz + hz);
        const float n = tanh_fast(in_ + r * hn);
        llc_store_u32(&h0g[(t & 1) * 25600 + (bb + gcb) * HH + j0 + gcj],
                      packf((1.0f - z) * n + z * hv0));
      }
      if (t >= 1 && t <= TT) {            // h1(t-1)
        const float ir  = D[3 * hs + gcj][gcb] + bi1[gcj];
        const float iz  = D[4 * hs + gcj][gcb] + bi1[hs + gcj];
        const float in_ = D[5 * hs + gcj][gcb] + bi1[2 * hs + gcj];
        const float hr  = D[6 * hs + gcj][gcb] + bh1[gcj];
        const float hz  = D[7 * hs + gcj][gcb] + bh1[hs + gcj];
        const float hn  = D[8 * hs + gcj][gcb] + bh1[2 * hs + gcj];
        const float r = sigm(ir + hr), z = sigm(iz + hz);
        const float n = tanh_fast(in_ + r * hn);
        llc_store_u32(&h1g[((t + 1) & 1) * 25600 + (bb + gcb) * HH + j0 + gcj],
                      packf((1.0f - z) * n + z * hv1));
      }
    }
  };
  auto poll_check = [&](int gr, uint tgt, uint v) {  // ONE sleepy wave, bounded
    if (wave == 0) {
      const uint* fp = &flags[gr * 64 + (lane & 15) * 4];
      for (int it = 0; it < 20000; ++it) {
        if (__all((int)((lane < 16 ? v : tgt) >= tgt))) break;
        __builtin_amdgcn_s_sleep(1);
        if (lane < 16) v = llc_load_u32(fp);
      }
    }
  };

  // ---- prologue: stage A(0) (initial zeros; flags trivially >= 0) ----
  uint wA[13], wB[13];
  float xtfA = 1.0f, xtfB;
  issue_w(wA, bbA, 0);

  for (int t = 0; t <= TT + 1; ++t) {
    // ================= PHASE A (step t, group A) =================
    unpack_w(wA, 0);
    if (tid < 32 && t < TT) xc[0][tid >> 2][tid & 3] = xtfA;
    __syncthreads();                                   // S1: LDS-A ready
    uint vB = (uint)t;                                 // prefetch poll-B
    if (wave == 0 && lane < 16)
      vB = llc_load_u32(&flags[gB * 64 + (lane & 15) * 4]);
    mfma_phase(0, bbA, t);
    __syncthreads();                                   // S2: D ready
    poll_check(gB, (uint)t, vB);                       // B data (t) ready?
    __syncthreads();                                   // S3: all may load B
    issue_w(wB, bbB, t);                               // B-RT hides under gates
    xtfB = 1.0f;
    if (tid < 32 && t > 0 && t < TT)
      xtfB = x[((bbB + (tid >> 2)) * TT + (t - 1)) * 8 + (tid & 3)];
    gates_phase(0, bbA, t);
    __syncthreads();                                   // S4: drains A-stores+wB
    if (tid == 0) llc_store_u32(&flags[gA * 64 + s * 4], (uint)(t + 1));

    // ================= PHASE B (step t, group B) =================
    unpack_w(wB, 1);
    if (tid < 32 && t < TT) xc[1][tid >> 2][tid & 3] = xtfB;
    __syncthreads();                                   // S5: LDS-B ready
    uint vA = (uint)(t + 1);                           // prefetch poll-A
    if (wave == 0 && lane < 16 && t < TT + 1)
      vA = llc_load_u32(&flags[gA * 64 + (lane & 15) * 4]);
    mfma_phase(1, bbB, t);
    __syncthreads();                                   // S6: D ready
    if (t < TT + 1) poll_check(gA, (uint)(t + 1), vA); // A data (t+1) ready?
    __syncthreads();                                   // S7: all may load A
    xtfA = 1.0f;
    if (t < TT + 1) {
      issue_w(wA, bbA, t + 1);                         // A-RT hides under gates
      if (tid < 32 && t + 1 < TT)
        xtfA = x[((bbA + (tid >> 2)) * TT + t) * 8 + (tid & 3)];
    }
    gates_phase(1, bbB, t);
    __syncthreads();                                   // S8: drains B-stores+wA
    if (tid == 0) llc_store_u32(&flags[gB * 64 + s * 4], (uint)(t + 1));
  }
}

extern "C" void kernel_launch(void* const* d_in, const int* in_sizes, int n_in,
                              void* d_out, int out_size, void* d_ws, size_t ws_size,
                              hipStream_t stream) {
  uint* ws = (uint*)d_ws;
  // ws layout (u32): h0g[2][128][200] @0, h1g[2][128][200] @51200,
  // flags (1024 u32, 16 groups) @102400. Total 413696 B; workspace >=819200 B
  // proven available (R10/R11 ran that size).
  hipMemsetAsync(d_ws, 0, (size_t)(102400 + 1024) * sizeof(uint), stream);
  gru2_mfma<<<128, 256, 0, stream>>>(
      (const float*)d_in[0],
      (const float*)d_in[1], (const float*)d_in[2],
      (const float*)d_in[3], (const float*)d_in[4],
      (const float*)d_in[5], (const float*)d_in[6],
      (const float*)d_in[7], (const float*)d_in[8],
      (const float*)d_in[9], (const float*)d_in[10],
      (float*)d_out, ws, ws + 51200, ws + 102400);
}